// Round 1
// baseline (173.864 us; speedup 1.0000x reference)
//
#include <hip/hip_runtime.h>
#include <cfloat>

#define HD 1024
#define LS 2048
#define NB 16
#define LCHUNK 64            // l-chunks for context partial
#define LPER   (LS / LCHUNK) // 32 rows per chunk

struct f4 { float x, y, z, w; };

__device__ inline f4 ld4(const float* p) { return *reinterpret_cast<const f4*>(p); }

__device__ inline float waveReduce(float v) {
    #pragma unroll
    for (int off = 32; off; off >>= 1) v += __shfl_xor(v, off, 64);
    return v;
}

__device__ inline float ftanh(float x) {
    x = fminf(10.f, fmaxf(-10.f, x));
    float t = __expf(2.f * x);
    return 1.f - 2.f * __builtin_amdgcn_rcpf(t + 1.f);
}

// ---- 1: qf[b][h] = bq[h] + query[b,:] . Wq[h,:] ----
__global__ void qf_kernel(const float* __restrict__ query, const float* __restrict__ Wq,
                          const float* __restrict__ bq, float* __restrict__ qf) {
    int wave = blockIdx.x * (blockDim.x >> 6) + (threadIdx.x >> 6);
    int lane = threadIdx.x & 63;
    int h = wave;
    if (h >= HD) return;
    float acc[NB];
    #pragma unroll
    for (int b = 0; b < NB; ++b) acc[b] = 0.f;
    #pragma unroll
    for (int it = 0; it < 4; ++it) {
        int k0 = it * 256 + lane * 4;
        f4 w = ld4(Wq + (size_t)h * HD + k0);
        #pragma unroll
        for (int b = 0; b < NB; ++b) {
            f4 q = ld4(query + b * HD + k0);
            acc[b] += w.x * q.x + w.y * q.y + w.z * q.z + w.w * q.w;
        }
    }
    #pragma unroll
    for (int b = 0; b < NB; ++b) {
        float r = waveReduce(acc[b]);
        if (lane == 0) qf[b * HD + h] = r + bq[h];
    }
}

// ---- 2: e[b][l] = mask ? sum_h tanh(qf + sf + cov*Wc) * v : -FLT_MAX ----
__global__ void align_kernel(const float* __restrict__ sf, const float* __restrict__ qf,
                             const float* __restrict__ Wc, const float* __restrict__ vv,
                             const float* __restrict__ coverage, const int* __restrict__ mask,
                             const int* __restrict__ is_cov_p, float* __restrict__ e) {
    int row = blockIdx.x * (blockDim.x >> 6) + (threadIdx.x >> 6);
    int lane = threadIdx.x & 63;
    if (row >= NB * LS) return;
    int b = row >> 11;
    float covs = (*is_cov_p) ? coverage[row] : 0.f;
    const float* sfr = sf + (size_t)row * HD;
    const float* qfr = qf + b * HD;
    float acc = 0.f;
    #pragma unroll
    for (int it = 0; it < 4; ++it) {
        int h0 = it * 256 + lane * 4;
        f4 s = ld4(sfr + h0);
        f4 q = ld4(qfr + h0);
        f4 wc = ld4(Wc + h0);
        f4 vf = ld4(vv + h0);
        float tx = ftanh(s.x + q.x + covs * wc.x);
        float ty = ftanh(s.y + q.y + covs * wc.y);
        float tz = ftanh(s.z + q.z + covs * wc.z);
        float tw = ftanh(s.w + q.w + covs * wc.w);
        acc += tx * vf.x + ty * vf.y + tz * vf.z + tw * vf.w;
    }
    acc = waveReduce(acc);
    if (lane == 0) e[row] = mask[row] ? acc : -FLT_MAX;
}

// ---- 3: softmax over L per batch; writes align_vectors + new_coverage to d_out ----
__global__ void softmax_kernel(const float* __restrict__ e, const float* __restrict__ coverage,
                               float* __restrict__ out_align, float* __restrict__ out_newcov) {
    int b = blockIdx.x;
    int t = threadIdx.x; // 256 threads, 8 vals each
    __shared__ float red[256];
    float vals[8];
    float mx = -FLT_MAX;
    #pragma unroll
    for (int i = 0; i < 8; ++i) {
        vals[i] = e[b * LS + t + i * 256];
        mx = fmaxf(mx, vals[i]);
    }
    red[t] = mx; __syncthreads();
    for (int s = 128; s; s >>= 1) { if (t < s) red[t] = fmaxf(red[t], red[t + s]); __syncthreads(); }
    mx = red[0]; __syncthreads();
    float sum = 0.f;
    #pragma unroll
    for (int i = 0; i < 8; ++i) { vals[i] = __expf(vals[i] - mx); sum += vals[i]; }
    red[t] = sum; __syncthreads();
    for (int s = 128; s; s >>= 1) { if (t < s) red[t] += red[t + s]; __syncthreads(); }
    float inv = 1.f / red[0];
    #pragma unroll
    for (int i = 0; i < 8; ++i) {
        int idx = b * LS + t + i * 256;
        float p = vals[i] * inv;
        out_align[idx] = p;
        out_newcov[idx] = coverage[idx] + p;
    }
}

// ---- 4a: partial context sums over l-chunks ----
__global__ void ctx_partial_kernel(const float* __restrict__ states, const float* __restrict__ align,
                                   float* __restrict__ partial) {
    int b = blockIdx.y;
    int chunk = blockIdx.x;
    int h0 = threadIdx.x * 4;
    float ax = 0.f, ay = 0.f, az = 0.f, aw = 0.f;
    int lbase = chunk * LPER;
    for (int i = 0; i < LPER; ++i) {
        int l = lbase + i;
        float a = align[b * LS + l];
        f4 s = ld4(states + ((size_t)(b * LS + l)) * HD + h0);
        ax += a * s.x; ay += a * s.y; az += a * s.z; aw += a * s.w;
    }
    f4 out; out.x = ax; out.y = ay; out.z = az; out.w = aw;
    *reinterpret_cast<f4*>(partial + ((size_t)(b * LCHUNK + chunk)) * HD + h0) = out;
}

// ---- 4b: reduce partials -> c[b][h] ----
__global__ void ctx_reduce_kernel(const float* __restrict__ partial, float* __restrict__ c) {
    int idx = blockIdx.x * 256 + threadIdx.x; // 0..16383
    int b = idx >> 10;
    int h = idx & 1023;
    float s = 0.f;
    #pragma unroll 8
    for (int ch = 0; ch < LCHUNK; ++ch) s += partial[((size_t)(b * LCHUNK + ch) << 10) + h];
    c[idx] = s;
}

// ---- 5: attn_h[b][h] = bout[h] + [c,query][b,:] . Wout[h,:] ----
__global__ void out_kernel(const float* __restrict__ c, const float* __restrict__ query,
                           const float* __restrict__ Wout, const float* __restrict__ bout,
                           float* __restrict__ attn) {
    int wave = blockIdx.x * (blockDim.x >> 6) + (threadIdx.x >> 6);
    int lane = threadIdx.x & 63;
    int h = wave;
    if (h >= HD) return;
    float acc[NB];
    #pragma unroll
    for (int b = 0; b < NB; ++b) acc[b] = 0.f;
    #pragma unroll
    for (int it = 0; it < 8; ++it) {
        int j0 = it * 256 + lane * 4;
        f4 w = ld4(Wout + (size_t)h * (2 * HD) + j0);
        const float* src = (j0 < HD) ? (c + j0) : (query + j0 - HD);
        #pragma unroll
        for (int b = 0; b < NB; ++b) {
            f4 x = ld4(src + b * HD);
            acc[b] += w.x * x.x + w.y * x.y + w.z * x.z + w.w * x.w;
        }
    }
    #pragma unroll
    for (int b = 0; b < NB; ++b) {
        float r = waveReduce(acc[b]);
        if (lane == 0) attn[b * HD + h] = r + bout[h];
    }
}

extern "C" void kernel_launch(void* const* d_in, const int* in_sizes, int n_in,
                              void* d_out, int out_size, void* d_ws, size_t ws_size,
                              hipStream_t stream) {
    const float* query    = (const float*)d_in[0];
    const float* states   = (const float*)d_in[1];
    const float* sf       = (const float*)d_in[2];
    const float* coverage = (const float*)d_in[3];
    const int*   mask     = (const int*)d_in[4];
    const int*   is_cov   = (const int*)d_in[5];
    const float* Wq       = (const float*)d_in[6];
    const float* bq       = (const float*)d_in[7];
    const float* Wc       = (const float*)d_in[8];
    const float* v        = (const float*)d_in[9];
    const float* Wout     = (const float*)d_in[10];
    const float* bout     = (const float*)d_in[11];

    float* out      = (float*)d_out;
    float* attn     = out;                 // (16,1,1024)  = 16384
    float* newcov   = out + 16384;         // (16,2048,1)  = 32768
    float* alignout = out + 49152;         // (16,2048,1)  = 32768

    float* w  = (float*)d_ws;
    float* qf      = w;                          // 16*1024
    float* e       = w + 16384;                  // 16*2048
    float* partial = w + 49152;                  // 16*64*1024 = 1048576
    float* c       = w + 49152 + 1048576;        // 16*1024

    // 1: query features
    qf_kernel<<<dim3(HD / 4), dim3(256), 0, stream>>>(query, Wq, bq, qf);
    // 2: alignment energies (reads states_features once, 128 MB)
    align_kernel<<<dim3((NB * LS) / 4), dim3(256), 0, stream>>>(sf, qf, Wc, v, coverage, mask, is_cov, e);
    // 3: softmax + outputs align_vectors / new_coverage
    softmax_kernel<<<dim3(NB), dim3(256), 0, stream>>>(e, coverage, alignout, newcov);
    // 4a: context partial sums (reads states once, 128 MB)
    ctx_partial_kernel<<<dim3(LCHUNK, NB), dim3(256), 0, stream>>>(states, alignout, partial);
    // 4b: reduce partials
    ctx_reduce_kernel<<<dim3((NB * HD) / 256), dim3(256), 0, stream>>>(partial, c);
    // 5: output projection
    out_kernel<<<dim3(HD / 4), dim3(256), 0, stream>>>(c, query, Wout, bout, attn);
}

// Round 2
// 86.251 us; speedup vs baseline: 2.0158x; 2.0158x over previous
//
#include <hip/hip_runtime.h>
#include <cfloat>

#define HD 1024
#define LS 2048
#define NB 16
#define LCHUNK 64            // l-chunks for context partial
#define LPER   (LS / LCHUNK) // 32 rows per chunk

struct f4 { float x, y, z, w; };

__device__ inline f4 ld4(const float* p) { return *reinterpret_cast<const f4*>(p); }

__device__ inline float waveReduce(float v) {
    #pragma unroll
    for (int off = 32; off; off >>= 1) v += __shfl_xor(v, off, 64);
    return v;
}

__device__ inline float ftanh(float x) {
    x = fminf(10.f, fmaxf(-10.f, x));
    float t = __expf(2.f * x);
    return 1.f - 2.f * __builtin_amdgcn_rcpf(t + 1.f);
}

// ---- 1: qf[b][h] = bq[h] + query[b,:] . Wq[h,:]  (block per h, k split over block) ----
__global__ void qf_kernel(const float* __restrict__ query, const float* __restrict__ Wq,
                          const float* __restrict__ bq, float* __restrict__ qf) {
    int h = blockIdx.x;
    int tid = threadIdx.x;            // 256
    int wv = tid >> 6, lane = tid & 63;
    int k0 = tid * 4;
    f4 w = ld4(Wq + (size_t)h * HD + k0);
    __shared__ float red[4][NB];
    float acc[NB];
    #pragma unroll
    for (int b = 0; b < NB; ++b) {
        f4 q = ld4(query + b * HD + k0);
        acc[b] = w.x * q.x + w.y * q.y + w.z * q.z + w.w * q.w;
    }
    #pragma unroll
    for (int b = 0; b < NB; ++b) {
        float r = waveReduce(acc[b]);
        if (lane == 0) red[wv][b] = r;
    }
    __syncthreads();
    if (tid < NB) {
        float s = red[0][tid] + red[1][tid] + red[2][tid] + red[3][tid];
        qf[tid * HD + h] = s + bq[h];
    }
}

// ---- 2: e[b][l] = mask ? sum_h tanh(qf + sf + cov*Wc) * v : -FLT_MAX  (wave per row) ----
__global__ void align_kernel(const float* __restrict__ sf, const float* __restrict__ qf,
                             const float* __restrict__ Wc, const float* __restrict__ vv,
                             const float* __restrict__ coverage, const int* __restrict__ mask,
                             const int* __restrict__ is_cov_p, float* __restrict__ e) {
    int row = blockIdx.x * (blockDim.x >> 6) + (threadIdx.x >> 6);
    int lane = threadIdx.x & 63;
    if (row >= NB * LS) return;
    int b = row >> 11;
    float covs = (*is_cov_p) ? coverage[row] : 0.f;
    const float* sfr = sf + (size_t)row * HD;
    const float* qfr = qf + b * HD;
    float acc = 0.f;
    #pragma unroll
    for (int it = 0; it < 4; ++it) {
        int h0 = it * 256 + lane * 4;
        f4 s = ld4(sfr + h0);
        f4 q = ld4(qfr + h0);
        f4 wc = ld4(Wc + h0);
        f4 vf = ld4(vv + h0);
        float tx = ftanh(s.x + q.x + covs * wc.x);
        float ty = ftanh(s.y + q.y + covs * wc.y);
        float tz = ftanh(s.z + q.z + covs * wc.z);
        float tw = ftanh(s.w + q.w + covs * wc.w);
        acc += tx * vf.x + ty * vf.y + tz * vf.z + tw * vf.w;
    }
    acc = waveReduce(acc);
    if (lane == 0) e[row] = mask[row] ? acc : -FLT_MAX;
}

// ---- 3: softmax over L per batch (block per b, 1024 threads) ----
__global__ void softmax_kernel(const float* __restrict__ e, const float* __restrict__ coverage,
                               float* __restrict__ out_align, float* __restrict__ out_newcov) {
    int b = blockIdx.x;
    int t = threadIdx.x;              // 1024
    int wv = t >> 6, lane = t & 63;
    __shared__ float redm[16], reds[16];
    float v0 = e[b * LS + t];
    float v1 = e[b * LS + t + 1024];
    float mx = fmaxf(v0, v1);
    #pragma unroll
    for (int off = 32; off; off >>= 1) mx = fmaxf(mx, __shfl_xor(mx, off, 64));
    if (lane == 0) redm[wv] = mx;
    __syncthreads();
    mx = redm[0];
    #pragma unroll
    for (int i = 1; i < 16; ++i) mx = fmaxf(mx, redm[i]);
    float e0 = __expf(v0 - mx), e1 = __expf(v1 - mx);
    float s = e0 + e1;
    #pragma unroll
    for (int off = 32; off; off >>= 1) s += __shfl_xor(s, off, 64);
    if (lane == 0) reds[wv] = s;
    __syncthreads();
    s = 0.f;
    #pragma unroll
    for (int i = 0; i < 16; ++i) s += reds[i];
    float inv = 1.f / s;
    int i0 = b * LS + t, i1 = i0 + 1024;
    float p0 = e0 * inv, p1 = e1 * inv;
    out_align[i0] = p0;
    out_align[i1] = p1;
    out_newcov[i0] = coverage[i0] + p0;
    out_newcov[i1] = coverage[i1] + p1;
}

// ---- 4a: partial context sums (512 threads: two l-rows in flight, LDS combine) ----
__global__ void ctx_partial_kernel(const float* __restrict__ states, const float* __restrict__ align,
                                   float* __restrict__ partial) {
    int b = blockIdx.y;
    int chunk = blockIdx.x;
    int half = threadIdx.x >> 8;      // 0 / 1
    int hh = threadIdx.x & 255;
    int h0 = hh * 4;
    float ax = 0.f, ay = 0.f, az = 0.f, aw = 0.f;
    int lbase = chunk * LPER;
    #pragma unroll 4
    for (int i = 0; i < LPER / 2; ++i) {
        int l = lbase + i * 2 + half;
        float a = align[b * LS + l];
        f4 s = ld4(states + ((size_t)(b * LS + l)) * HD + h0);
        ax += a * s.x; ay += a * s.y; az += a * s.z; aw += a * s.w;
    }
    __shared__ float red[256 * 4];
    if (half == 1) {
        red[hh * 4 + 0] = ax; red[hh * 4 + 1] = ay;
        red[hh * 4 + 2] = az; red[hh * 4 + 3] = aw;
    }
    __syncthreads();
    if (half == 0) {
        f4 out;
        out.x = ax + red[hh * 4 + 0];
        out.y = ay + red[hh * 4 + 1];
        out.z = az + red[hh * 4 + 2];
        out.w = aw + red[hh * 4 + 3];
        *reinterpret_cast<f4*>(partial + ((size_t)(b * LCHUNK + chunk)) * HD + h0) = out;
    }
}

// ---- 4b: reduce partials -> c[b][h] ----
__global__ void ctx_reduce_kernel(const float* __restrict__ partial, float* __restrict__ c) {
    int idx = blockIdx.x * 256 + threadIdx.x; // 0..16383
    int b = idx >> 10;
    int h = idx & 1023;
    float s = 0.f;
    #pragma unroll 8
    for (int ch = 0; ch < LCHUNK; ++ch) s += partial[((size_t)(b * LCHUNK + ch) << 10) + h];
    c[idx] = s;
}

// ---- 5: attn_h[b][h] = bout[h] + [c,query][b,:] . Wout[h,:]  (block per h) ----
__global__ void out_kernel(const float* __restrict__ c, const float* __restrict__ query,
                           const float* __restrict__ Wout, const float* __restrict__ bout,
                           float* __restrict__ attn) {
    int h = blockIdx.x;
    int tid = threadIdx.x;            // 256
    int wv = tid >> 6, lane = tid & 63;
    int j0 = tid * 8;
    const float* wr = Wout + (size_t)h * (2 * HD);
    f4 w0 = ld4(wr + j0);
    f4 w1 = ld4(wr + j0 + 4);
    const float* src = (j0 < HD) ? (c + j0) : (query + j0 - HD);
    __shared__ float red[4][NB];
    float acc[NB];
    #pragma unroll
    for (int b = 0; b < NB; ++b) {
        f4 x0 = ld4(src + b * HD);
        f4 x1 = ld4(src + b * HD + 4);
        acc[b] = w0.x * x0.x + w0.y * x0.y + w0.z * x0.z + w0.w * x0.w
               + w1.x * x1.x + w1.y * x1.y + w1.z * x1.z + w1.w * x1.w;
    }
    #pragma unroll
    for (int b = 0; b < NB; ++b) {
        float r = waveReduce(acc[b]);
        if (lane == 0) red[wv][b] = r;
    }
    __syncthreads();
    if (tid < NB) {
        float s = red[0][tid] + red[1][tid] + red[2][tid] + red[3][tid];
        attn[tid * HD + h] = s + bout[h];
    }
}

extern "C" void kernel_launch(void* const* d_in, const int* in_sizes, int n_in,
                              void* d_out, int out_size, void* d_ws, size_t ws_size,
                              hipStream_t stream) {
    const float* query    = (const float*)d_in[0];
    const float* states   = (const float*)d_in[1];
    const float* sf       = (const float*)d_in[2];
    const float* coverage = (const float*)d_in[3];
    const int*   mask     = (const int*)d_in[4];
    const int*   is_cov   = (const int*)d_in[5];
    const float* Wq       = (const float*)d_in[6];
    const float* bq       = (const float*)d_in[7];
    const float* Wc       = (const float*)d_in[8];
    const float* v        = (const float*)d_in[9];
    const float* Wout     = (const float*)d_in[10];
    const float* bout     = (const float*)d_in[11];

    float* out      = (float*)d_out;
    float* attn     = out;                 // (16,1,1024)  = 16384
    float* newcov   = out + 16384;         // (16,2048,1)  = 32768
    float* alignout = out + 49152;         // (16,2048,1)  = 32768

    float* w  = (float*)d_ws;
    float* qf      = w;                          // 16*1024
    float* e       = w + 16384;                  // 16*2048
    float* partial = w + 49152;                  // 16*64*1024 = 1048576
    float* c       = w + 49152 + 1048576;        // 16*1024

    // 1: query features (reads Wq once, 4 MB)
    qf_kernel<<<dim3(HD), dim3(256), 0, stream>>>(query, Wq, bq, qf);
    // 2: alignment energies (reads states_features once, 128 MB)
    align_kernel<<<dim3((NB * LS) / 4), dim3(256), 0, stream>>>(sf, qf, Wc, v, coverage, mask, is_cov, e);
    // 3: softmax + outputs align_vectors / new_coverage
    softmax_kernel<<<dim3(NB), dim3(1024), 0, stream>>>(e, coverage, alignout, newcov);
    // 4a: context partial sums (reads states once, 128 MB)
    ctx_partial_kernel<<<dim3(LCHUNK, NB), dim3(512), 0, stream>>>(states, alignout, partial);
    // 4b: reduce partials
    ctx_reduce_kernel<<<dim3((NB * HD) / 256), dim3(256), 0, stream>>>(partial, c);
    // 5: output projection (reads Wout once, 8 MB)
    out_kernel<<<dim3(HD), dim3(256), 0, stream>>>(c, query, Wout, bout, attn);
}

// Round 3
// 82.705 us; speedup vs baseline: 2.1022x; 1.0429x over previous
//
#include <hip/hip_runtime.h>
#include <cfloat>

#define HD 1024
#define LS 2048
#define NB 16
#define LCHUNK 64            // l-chunks
#define LPER   (LS / LCHUNK) // 32 rows per chunk

struct f4 { float x, y, z, w; };

__device__ inline f4 ld4(const float* p) { return *reinterpret_cast<const f4*>(p); }

__device__ inline float waveReduce(float v) {
    #pragma unroll
    for (int off = 32; off; off >>= 1) v += __shfl_xor(v, off, 64);
    return v;
}

__device__ inline float ftanh(float x) {
    x = fminf(10.f, fmaxf(-10.f, x));
    float t = __expf(2.f * x);
    return 1.f - 2.f * __builtin_amdgcn_rcpf(t + 1.f);
}

// ---- 1: qf[b][h] = bq[h] + query[b,:] . Wq[h,:]  (block per h) ----
__global__ void qf_kernel(const float* __restrict__ query, const float* __restrict__ Wq,
                          const float* __restrict__ bq, float* __restrict__ qf) {
    int h = blockIdx.x;
    int tid = threadIdx.x;            // 256
    int wv = tid >> 6, lane = tid & 63;
    int k0 = tid * 4;
    f4 w = ld4(Wq + (size_t)h * HD + k0);
    __shared__ float red[4][NB];
    float acc[NB];
    #pragma unroll
    for (int b = 0; b < NB; ++b) {
        f4 q = ld4(query + b * HD + k0);
        acc[b] = w.x * q.x + w.y * q.y + w.z * q.z + w.w * q.w;
    }
    #pragma unroll
    for (int b = 0; b < NB; ++b) {
        float r = waveReduce(acc[b]);
        if (lane == 0) red[wv][b] = r;
    }
    __syncthreads();
    if (tid < NB) {
        float s = red[0][tid] + red[1][tid] + red[2][tid] + red[3][tid];
        qf[tid * HD + h] = s + bq[h];
    }
}

// ---- 2 (fused): per (b,chunk): energies + chunk-softmax stats + exp-weighted
//      partial context. Reads states_features AND states exactly once. ----
__global__ void fused_kernel(const float* __restrict__ sf, const float* __restrict__ qf,
                             const float* __restrict__ Wc, const float* __restrict__ vv,
                             const float* __restrict__ coverage, const int* __restrict__ mask,
                             const int* __restrict__ is_cov_p,
                             const float* __restrict__ states,
                             float* __restrict__ e_out,   // [NB][LS]
                             float* __restrict__ cpart,   // [NB][LCHUNK][HD]
                             float* __restrict__ mchunk,  // [NB][LCHUNK]
                             float* __restrict__ tchunk)  // [NB][LCHUNK]
{
    int chunk = blockIdx.x;
    int b = blockIdx.y;
    int tid = threadIdx.x;            // 512
    int wv = tid >> 6, lane = tid & 63;   // 8 waves
    int lbase = chunk * LPER;

    __shared__ float e_loc[LPER];
    __shared__ float w_loc[LPER];

    // phase 1: each wave computes 4 rows' energies
    int covflag = *is_cov_p;
    const float* qfr = qf + b * HD;
    #pragma unroll
    for (int i = 0; i < 4; ++i) {
        int r = wv * 4 + i;
        int row = b * LS + lbase + r;
        float covs = covflag ? coverage[row] : 0.f;
        const float* sfr = sf + (size_t)row * HD;
        float acc = 0.f;
        #pragma unroll
        for (int it = 0; it < 4; ++it) {
            int h0 = it * 256 + lane * 4;
            f4 s = ld4(sfr + h0);
            f4 q = ld4(qfr + h0);
            f4 wc = ld4(Wc + h0);
            f4 vf = ld4(vv + h0);
            acc += ftanh(s.x + q.x + covs * wc.x) * vf.x
                 + ftanh(s.y + q.y + covs * wc.y) * vf.y
                 + ftanh(s.z + q.z + covs * wc.z) * vf.z
                 + ftanh(s.w + q.w + covs * wc.w) * vf.w;
        }
        acc = waveReduce(acc);
        if (lane == 0) {
            float ev = mask[row] ? acc : -FLT_MAX;
            e_loc[r] = ev;
            e_out[row] = ev;
        }
    }
    __syncthreads();

    // chunk max (broadcast reads from LDS, every thread computes it)
    float m_c = -1e30f;
    #pragma unroll
    for (int i = 0; i < LPER; ++i) m_c = fmaxf(m_c, e_loc[i]);

    // weights
    if (tid < LPER) {
        float ev = e_loc[tid];
        w_loc[tid] = (ev == -FLT_MAX) ? 0.f : __expf(ev - m_c);
    }
    __syncthreads();

    if (tid == 0) {
        float t = 0.f;
        #pragma unroll
        for (int i = 0; i < LPER; ++i) t += w_loc[i];
        mchunk[b * LCHUNK + chunk] = m_c;
        tchunk[b * LCHUNK + chunk] = t;
    }

    // phase 2: exp-weighted partial context over this chunk's rows
    int half = tid >> 8;              // 0/1
    int hh = tid & 255;
    int h0 = hh * 4;
    float ax = 0.f, ay = 0.f, az = 0.f, aw = 0.f;
    #pragma unroll 8
    for (int i = 0; i < LPER / 2; ++i) {
        int r = i * 2 + half;
        float wgt = w_loc[r];
        f4 s = ld4(states + ((size_t)(b * LS + lbase + r)) * HD + h0);
        ax += wgt * s.x; ay += wgt * s.y; az += wgt * s.z; aw += wgt * s.w;
    }
    __shared__ float red2[256 * 4];
    if (half == 1) {
        red2[hh * 4 + 0] = ax; red2[hh * 4 + 1] = ay;
        red2[hh * 4 + 2] = az; red2[hh * 4 + 3] = aw;
    }
    __syncthreads();
    if (half == 0) {
        f4 o;
        o.x = ax + red2[hh * 4 + 0];
        o.y = ay + red2[hh * 4 + 1];
        o.z = az + red2[hh * 4 + 2];
        o.w = aw + red2[hh * 4 + 3];
        *reinterpret_cast<f4*>(cpart + ((size_t)(b * LCHUNK + chunk)) * HD + h0) = o;
    }
}

// ---- 3: combine chunk stats; write align_vectors, new_coverage, chunk scales ----
__global__ void finalize_kernel(const float* __restrict__ e, const float* __restrict__ mchunk,
                                const float* __restrict__ tchunk, const float* __restrict__ coverage,
                                float* __restrict__ scale, float* __restrict__ out_align,
                                float* __restrict__ out_newcov) {
    int b = blockIdx.x;
    int t = threadIdx.x; // 1024
    __shared__ float mc_s[LCHUNK], tc_s[LCHUNK];
    __shared__ float sm, sz;
    if (t < LCHUNK) { mc_s[t] = mchunk[b * LCHUNK + t]; tc_s[t] = tchunk[b * LCHUNK + t]; }
    __syncthreads();
    if (t == 0) {
        float m = -1e30f;
        #pragma unroll
        for (int i = 0; i < LCHUNK; ++i) m = fmaxf(m, mc_s[i]);
        float Z = 0.f;
        #pragma unroll
        for (int i = 0; i < LCHUNK; ++i) Z += tc_s[i] * __expf(mc_s[i] - m);
        sm = m; sz = Z;
    }
    __syncthreads();
    float m = sm;
    float invZ = 1.f / sz;
    if (t < LCHUNK) scale[b * LCHUNK + t] = __expf(mc_s[t] - m) * invZ;
    int i0 = b * LS + t, i1 = i0 + 1024;
    float p0 = __expf(e[i0] - m) * invZ;
    float p1 = __expf(e[i1] - m) * invZ;
    out_align[i0] = p0;
    out_align[i1] = p1;
    out_newcov[i0] = coverage[i0] + p0;
    out_newcov[i1] = coverage[i1] + p1;
}

// ---- 4: c[b][h] = sum_ch scale[b][ch] * cpart[b][ch][h] ----
__global__ void ctx_reduce_kernel(const float* __restrict__ cpart, const float* __restrict__ scale,
                                  float* __restrict__ c) {
    int idx = blockIdx.x * 256 + threadIdx.x; // 0..16383
    int b = idx >> 10;
    int h = idx & 1023;
    float s = 0.f;
    #pragma unroll 8
    for (int ch = 0; ch < LCHUNK; ++ch)
        s += scale[b * LCHUNK + ch] * cpart[((size_t)(b * LCHUNK + ch) << 10) + h];
    c[idx] = s;
}

// ---- 5: attn_h[b][h] = bout[h] + [c,query][b,:] . Wout[h,:]  (block per h) ----
__global__ void out_kernel(const float* __restrict__ c, const float* __restrict__ query,
                           const float* __restrict__ Wout, const float* __restrict__ bout,
                           float* __restrict__ attn) {
    int h = blockIdx.x;
    int tid = threadIdx.x;            // 256
    int wv = tid >> 6, lane = tid & 63;
    int j0 = tid * 8;
    const float* wr = Wout + (size_t)h * (2 * HD);
    f4 w0 = ld4(wr + j0);
    f4 w1 = ld4(wr + j0 + 4);
    const float* src = (j0 < HD) ? (c + j0) : (query + j0 - HD);
    __shared__ float red[4][NB];
    float acc[NB];
    #pragma unroll
    for (int b = 0; b < NB; ++b) {
        f4 x0 = ld4(src + b * HD);
        f4 x1 = ld4(src + b * HD + 4);
        acc[b] = w0.x * x0.x + w0.y * x0.y + w0.z * x0.z + w0.w * x0.w
               + w1.x * x1.x + w1.y * x1.y + w1.z * x1.z + w1.w * x1.w;
    }
    #pragma unroll
    for (int b = 0; b < NB; ++b) {
        float r = waveReduce(acc[b]);
        if (lane == 0) red[wv][b] = r;
    }
    __syncthreads();
    if (tid < NB) {
        float s = red[0][tid] + red[1][tid] + red[2][tid] + red[3][tid];
        attn[tid * HD + h] = s + bout[h];
    }
}

extern "C" void kernel_launch(void* const* d_in, const int* in_sizes, int n_in,
                              void* d_out, int out_size, void* d_ws, size_t ws_size,
                              hipStream_t stream) {
    const float* query    = (const float*)d_in[0];
    const float* states   = (const float*)d_in[1];
    const float* sf       = (const float*)d_in[2];
    const float* coverage = (const float*)d_in[3];
    const int*   mask     = (const int*)d_in[4];
    const int*   is_cov   = (const int*)d_in[5];
    const float* Wq       = (const float*)d_in[6];
    const float* bq       = (const float*)d_in[7];
    const float* Wc       = (const float*)d_in[8];
    const float* v        = (const float*)d_in[9];
    const float* Wout     = (const float*)d_in[10];
    const float* bout     = (const float*)d_in[11];

    float* out      = (float*)d_out;
    float* attn     = out;                 // (16,1,1024)  = 16384
    float* newcov   = out + 16384;         // (16,2048,1)  = 32768
    float* alignout = out + 49152;         // (16,2048,1)  = 32768

    float* w  = (float*)d_ws;
    float* qf      = w;                          // 16*1024          = 16384
    float* e       = w + 16384;                  // 16*2048          = 32768
    float* cpart   = w + 49152;                  // 16*64*1024       = 1048576
    float* mchunk  = w + 49152 + 1048576;        // 16*64            = 1024
    float* tchunk  = mchunk + 1024;              // 16*64            = 1024
    float* scale   = tchunk + 1024;              // 16*64            = 1024
    float* c       = scale + 1024;               // 16*1024          = 16384

    // 1: query features (reads Wq once, 4 MB)
    qf_kernel<<<dim3(HD), dim3(256), 0, stream>>>(query, Wq, bq, qf);
    // 2: fused energies + chunk softmax stats + weighted partial context
    //    (reads states_features + states once: 256 MB in one dispatch)
    fused_kernel<<<dim3(LCHUNK, NB), dim3(512), 0, stream>>>(
        sf, qf, Wc, v, coverage, mask, is_cov, states, e, cpart, mchunk, tchunk);
    // 3: combine chunk stats; align_vectors + new_coverage + scales
    finalize_kernel<<<dim3(NB), dim3(1024), 0, stream>>>(e, mchunk, tchunk, coverage,
                                                         scale, alignout, newcov);
    // 4: scaled reduce of partials -> c
    ctx_reduce_kernel<<<dim3((NB * HD) / 256), dim3(256), 0, stream>>>(cpart, scale, c);
    // 5: output projection (reads Wout once, 8 MB)
    out_kernel<<<dim3(HD), dim3(256), 0, stream>>>(c, query, Wout, bout, attn);
}

// Round 4
// 69.167 us; speedup vs baseline: 2.5137x; 1.1957x over previous
//
#include <hip/hip_runtime.h>
#include <cfloat>

#define HD 1024
#define LS 2048
#define NB 16
#define LCHUNK 64            // chunks per batch in ctx kernel
#define LPER   (LS / LCHUNK) // 32 rows per chunk

struct f4 { float x, y, z, w; };

__device__ inline f4 ld4(const float* p) { return *reinterpret_cast<const f4*>(p); }

__device__ inline float waveReduce(float v) {
    #pragma unroll
    for (int off = 32; off; off >>= 1) v += __shfl_xor(v, off, 64);
    return v;
}

__device__ inline float ftanh(float x) {
    x = fminf(10.f, fmaxf(-10.f, x));
    float t = __expf(2.f * x);
    return 1.f - 2.f * __builtin_amdgcn_rcpf(t + 1.f);
}

__device__ inline float dotTanh(const f4& s, const f4& q, const f4& wc, const f4& v, float covs) {
    return ftanh(s.x + q.x + covs * wc.x) * v.x
         + ftanh(s.y + q.y + covs * wc.y) * v.y
         + ftanh(s.z + q.z + covs * wc.z) * v.z
         + ftanh(s.w + q.w + covs * wc.w) * v.w;
}

// ---- 1: qf[b][h] = bq[h] + query[b,:] . Wq[h,:]  (block per h) ----
__global__ void qf_kernel(const float* __restrict__ query, const float* __restrict__ Wq,
                          const float* __restrict__ bq, float* __restrict__ qf) {
    int h = blockIdx.x;
    int tid = threadIdx.x;            // 256
    int wv = tid >> 6, lane = tid & 63;
    int k0 = tid * 4;
    f4 w = ld4(Wq + (size_t)h * HD + k0);
    __shared__ float red[4][NB];
    float acc[NB];
    #pragma unroll
    for (int b = 0; b < NB; ++b) {
        f4 q = ld4(query + b * HD + k0);
        acc[b] = w.x * q.x + w.y * q.y + w.z * q.z + w.w * q.w;
    }
    #pragma unroll
    for (int b = 0; b < NB; ++b) {
        float r = waveReduce(acc[b]);
        if (lane == 0) red[wv][b] = r;
    }
    __syncthreads();
    if (tid < NB) {
        float s = red[0][tid] + red[1][tid] + red[2][tid] + red[3][tid];
        qf[tid * HD + h] = s + bq[h];
    }
}

// ---- 2: energies, mask-skipped. 2048 blocks x 256 thr; wave handles 4 rows. ----
__global__ __launch_bounds__(256) void energy_kernel(
    const float* __restrict__ sf, const float* __restrict__ qf,
    const float* __restrict__ Wc, const float* __restrict__ vv,
    const float* __restrict__ coverage, const int* __restrict__ mask,
    const int* __restrict__ is_cov_p, float* __restrict__ e_out)
{
    int b = blockIdx.x >> 7;                 // 128 blocks per batch
    int rbase = (blockIdx.x & 127) * 16;     // 16 rows per block
    int wv = threadIdx.x >> 6, lane = threadIdx.x & 63;
    int covflag = *is_cov_p;
    int l4 = lane * 4;

    // per-lane operand slice lives in registers for the whole block
    const float* qfr = qf + b * HD + l4;
    f4 q0 = ld4(qfr), q1 = ld4(qfr + 256), q2 = ld4(qfr + 512), q3 = ld4(qfr + 768);
    f4 w0 = ld4(Wc + l4), w1 = ld4(Wc + 256 + l4), w2 = ld4(Wc + 512 + l4), w3 = ld4(Wc + 768 + l4);
    f4 v0 = ld4(vv + l4), v1 = ld4(vv + 256 + l4), v2 = ld4(vv + 512 + l4), v3 = ld4(vv + 768 + l4);

    int r0 = rbase + wv * 4;
    #pragma unroll
    for (int i = 0; i < 4; i += 2) {
        int rowA = b * LS + r0 + i;
        int rowB = rowA + 1;
        bool mA = mask[rowA] != 0;
        bool mB = mask[rowB] != 0;
        const float* pA = sf + (size_t)rowA * HD + l4;
        const float* pB = sf + (size_t)rowB * HD + l4;
        f4 a0, a1, a2, a3, c0, c1, c2, c3;
        // issue both rows' loads before either compute -> MLP
        if (mA) { a0 = ld4(pA); a1 = ld4(pA + 256); a2 = ld4(pA + 512); a3 = ld4(pA + 768); }
        if (mB) { c0 = ld4(pB); c1 = ld4(pB + 256); c2 = ld4(pB + 512); c3 = ld4(pB + 768); }
        if (mA) {
            float covs = covflag ? coverage[rowA] : 0.f;
            float acc = dotTanh(a0, q0, w0, v0, covs) + dotTanh(a1, q1, w1, v1, covs)
                      + dotTanh(a2, q2, w2, v2, covs) + dotTanh(a3, q3, w3, v3, covs);
            acc = waveReduce(acc);
            if (lane == 0) e_out[rowA] = acc;
        } else if (lane == 0) {
            e_out[rowA] = -1e30f;
        }
        if (mB) {
            float covs = covflag ? coverage[rowB] : 0.f;
            float acc = dotTanh(c0, q0, w0, v0, covs) + dotTanh(c1, q1, w1, v1, covs)
                      + dotTanh(c2, q2, w2, v2, covs) + dotTanh(c3, q3, w3, v3, covs);
            acc = waveReduce(acc);
            if (lane == 0) e_out[rowB] = acc;
        } else if (lane == 0) {
            e_out[rowB] = -1e30f;
        }
    }
}

// ---- 3: raw-exp weighted partial contexts (no max shift; |e| <= ~26 so safe).
//      Reads states only for weight!=0 rows. ----
__global__ __launch_bounds__(512) void ctx_kernel(const float* __restrict__ e,
                                                  const float* __restrict__ states,
                                                  float* __restrict__ cpart) {
    int chunk = blockIdx.x;
    int b = blockIdx.y;
    int tid = threadIdx.x;            // 512
    __shared__ float w_loc[LPER];
    if (tid < LPER) w_loc[tid] = __expf(e[b * LS + chunk * LPER + tid]); // masked -> exp(-1e30)=0
    __syncthreads();
    int half = tid >> 8;              // 0/1
    int hh = tid & 255;
    int h0 = hh * 4;
    const float* base = states + ((size_t)(b * LS + chunk * LPER + half)) * HD + h0;
    float ax = 0.f, ay = 0.f, az = 0.f, aw = 0.f;
    #pragma unroll
    for (int i = 0; i < LPER / 2; ++i) {
        float wgt = w_loc[i * 2 + half];
        if (wgt != 0.f) {
            f4 s = ld4(base + (size_t)(i * 2) * HD);
            ax = fmaf(wgt, s.x, ax); ay = fmaf(wgt, s.y, ay);
            az = fmaf(wgt, s.z, az); aw = fmaf(wgt, s.w, aw);
        }
    }
    __shared__ float red2[256 * 4];
    if (half == 1) {
        red2[hh * 4 + 0] = ax; red2[hh * 4 + 1] = ay;
        red2[hh * 4 + 2] = az; red2[hh * 4 + 3] = aw;
    }
    __syncthreads();
    if (half == 0) {
        f4 o;
        o.x = ax + red2[hh * 4 + 0];
        o.y = ay + red2[hh * 4 + 1];
        o.z = az + red2[hh * 4 + 2];
        o.w = aw + red2[hh * 4 + 3];
        *reinterpret_cast<f4*>(cpart + ((size_t)(b * LCHUNK + chunk)) * HD + h0) = o;
    }
}

// ---- 4: per-batch softmax stats; align_vectors, new_coverage, scale = 1/sum(exp(e)) ----
__global__ void finalize_kernel(const float* __restrict__ e, const float* __restrict__ coverage,
                                float* __restrict__ scale, float* __restrict__ out_align,
                                float* __restrict__ out_newcov) {
    int b = blockIdx.x;
    int t = threadIdx.x;              // 1024
    int wv = t >> 6, lane = t & 63;
    __shared__ float redm[16], reds[16];
    float v0 = e[b * LS + t];
    float v1 = e[b * LS + t + 1024];
    float mx = fmaxf(v0, v1);
    #pragma unroll
    for (int off = 32; off; off >>= 1) mx = fmaxf(mx, __shfl_xor(mx, off, 64));
    if (lane == 0) redm[wv] = mx;
    __syncthreads();
    mx = redm[0];
    #pragma unroll
    for (int i = 1; i < 16; ++i) mx = fmaxf(mx, redm[i]);
    float e0 = __expf(v0 - mx), e1 = __expf(v1 - mx);
    float s = e0 + e1;
    #pragma unroll
    for (int off = 32; off; off >>= 1) s += __shfl_xor(s, off, 64);
    if (lane == 0) reds[wv] = s;
    __syncthreads();
    s = 0.f;
    #pragma unroll
    for (int i = 0; i < 16; ++i) s += reds[i];
    float invZ = 1.f / s;
    if (t == 0) scale[b] = __expf(-mx) * invZ;   // = 1 / sum(exp(e))
    int i0 = b * LS + t, i1 = i0 + 1024;
    float p0 = e0 * invZ, p1 = e1 * invZ;
    out_align[i0] = p0;
    out_align[i1] = p1;
    out_newcov[i0] = coverage[i0] + p0;
    out_newcov[i1] = coverage[i1] + p1;
}

// ---- 5: c[b][h] = scale[b] * sum_ch cpart[b][ch][h] ----
__global__ void ctx_reduce_kernel(const float* __restrict__ cpart, const float* __restrict__ scale,
                                  float* __restrict__ c) {
    int idx = blockIdx.x * 256 + threadIdx.x; // 0..16383
    int b = idx >> 10;
    int h = idx & 1023;
    const float* p = cpart + ((size_t)b * LCHUNK << 10) + h;
    float s0 = 0.f, s1 = 0.f, s2 = 0.f, s3 = 0.f;
    #pragma unroll 4
    for (int ch = 0; ch < LCHUNK; ch += 4) {
        s0 += p[(size_t)(ch + 0) << 10];
        s1 += p[(size_t)(ch + 1) << 10];
        s2 += p[(size_t)(ch + 2) << 10];
        s3 += p[(size_t)(ch + 3) << 10];
    }
    c[idx] = (s0 + s1 + s2 + s3) * scale[b];
}

// ---- 6: attn_h[b][h] = bout[h] + [c,query][b,:] . Wout[h,:]  (block per h) ----
__global__ void out_kernel(const float* __restrict__ c, const float* __restrict__ query,
                           const float* __restrict__ Wout, const float* __restrict__ bout,
                           float* __restrict__ attn) {
    int h = blockIdx.x;
    int tid = threadIdx.x;            // 256
    int wv = tid >> 6, lane = tid & 63;
    int j0 = tid * 8;
    const float* wr = Wout + (size_t)h * (2 * HD);
    f4 w0 = ld4(wr + j0);
    f4 w1 = ld4(wr + j0 + 4);
    const float* src = (j0 < HD) ? (c + j0) : (query + j0 - HD);
    __shared__ float red[4][NB];
    float acc[NB];
    #pragma unroll
    for (int b = 0; b < NB; ++b) {
        f4 x0 = ld4(src + b * HD);
        f4 x1 = ld4(src + b * HD + 4);
        acc[b] = w0.x * x0.x + w0.y * x0.y + w0.z * x0.z + w0.w * x0.w
               + w1.x * x1.x + w1.y * x1.y + w1.z * x1.z + w1.w * x1.w;
    }
    #pragma unroll
    for (int b = 0; b < NB; ++b) {
        float r = waveReduce(acc[b]);
        if (lane == 0) red[wv][b] = r;
    }
    __syncthreads();
    if (tid < NB) {
        float s = red[0][tid] + red[1][tid] + red[2][tid] + red[3][tid];
        attn[tid * HD + h] = s + bout[h];
    }
}

extern "C" void kernel_launch(void* const* d_in, const int* in_sizes, int n_in,
                              void* d_out, int out_size, void* d_ws, size_t ws_size,
                              hipStream_t stream) {
    const float* query    = (const float*)d_in[0];
    const float* states   = (const float*)d_in[1];
    const float* sf       = (const float*)d_in[2];
    const float* coverage = (const float*)d_in[3];
    const int*   mask     = (const int*)d_in[4];
    const int*   is_cov   = (const int*)d_in[5];
    const float* Wq       = (const float*)d_in[6];
    const float* bq       = (const float*)d_in[7];
    const float* Wc       = (const float*)d_in[8];
    const float* v        = (const float*)d_in[9];
    const float* Wout     = (const float*)d_in[10];
    const float* bout     = (const float*)d_in[11];

    float* out      = (float*)d_out;
    float* attn     = out;                 // (16,1,1024)  = 16384
    float* newcov   = out + 16384;         // (16,2048,1)  = 32768
    float* alignout = out + 49152;         // (16,2048,1)  = 32768

    float* w  = (float*)d_ws;
    float* qf      = w;                          // 16*1024    = 16384
    float* e       = w + 16384;                  // 16*2048    = 32768
    float* cpart   = w + 49152;                  // 16*64*1024 = 1048576
    float* scale   = w + 49152 + 1048576;        // 16
    float* c       = scale + 16;                 // 16*1024

    // 1: query features (reads Wq once, 4 MB)
    qf_kernel<<<dim3(HD), dim3(256), 0, stream>>>(query, Wq, bq, qf);
    // 2: energies, mask-skipped (~64 MB of states_features on average)
    energy_kernel<<<dim3(2048), dim3(256), 0, stream>>>(sf, qf, Wc, v, coverage, mask, is_cov, e);
    // 3: raw-exp weighted partial contexts (~64 MB of states on average)
    ctx_kernel<<<dim3(LCHUNK, NB), dim3(512), 0, stream>>>(e, states, cpart);
    // 4: softmax stats + align_vectors + new_coverage + scale
    finalize_kernel<<<dim3(NB), dim3(1024), 0, stream>>>(e, coverage, scale, alignout, newcov);
    // 5: scaled reduce of partials -> c
    ctx_reduce_kernel<<<dim3((NB * HD) / 256), dim3(256), 0, stream>>>(cpart, scale, c);
    // 6: output projection (reads Wout once, 8 MB)
    out_kernel<<<dim3(HD), dim3(256), 0, stream>>>(c, query, Wout, bout, attn);
}

// Round 5
// 59.875 us; speedup vs baseline: 2.9038x; 1.1552x over previous
//
#include <hip/hip_runtime.h>
#include <cfloat>

#define HD 1024
#define LS 2048
#define NB 16
#define LCHUNK 64            // chunks per batch in ctx kernel
#define LPER   (LS / LCHUNK) // 32 rows per chunk

struct f4 { float x, y, z, w; };

__device__ inline f4 ld4(const float* p) { return *reinterpret_cast<const f4*>(p); }

__device__ inline float ftanh(float x) {
    x = fminf(10.f, fmaxf(-10.f, x));
    float t = __expf(2.f * x);
    return 1.f - 2.f * __builtin_amdgcn_rcpf(t + 1.f);
}

__device__ inline float dotTanh(const f4& s, const f4& q, const f4& wc, const f4& v, float covs) {
    return ftanh(s.x + q.x + covs * wc.x) * v.x
         + ftanh(s.y + q.y + covs * wc.y) * v.y
         + ftanh(s.z + q.z + covs * wc.z) * v.z
         + ftanh(s.w + q.w + covs * wc.w) * v.w;
}

__device__ inline float waveReduce(float v) {
    #pragma unroll
    for (int off = 32; off; off >>= 1) v += __shfl_xor(v, off, 64);
    return v;
}

// ---- 1: qf[b][h] = bq[h] + query[b,:] . Wq[h,:]  (block per h) ----
__global__ void qf_kernel(const float* __restrict__ query, const float* __restrict__ Wq,
                          const float* __restrict__ bq, float* __restrict__ qf) {
    int h = blockIdx.x;
    int tid = threadIdx.x;            // 256
    int wv = tid >> 6, lane = tid & 63;
    int k0 = tid * 4;
    f4 w = ld4(Wq + (size_t)h * HD + k0);
    __shared__ float red[4][NB];
    float acc[NB];
    #pragma unroll
    for (int b = 0; b < NB; ++b) {
        f4 q = ld4(query + b * HD + k0);
        acc[b] = w.x * q.x + w.y * q.y + w.z * q.z + w.w * q.w;
    }
    #pragma unroll
    for (int b = 0; b < NB; ++b) {
        float r = waveReduce(acc[b]);
        if (lane == 0) red[wv][b] = r;
    }
    __syncthreads();
    if (tid < NB) {
        float s = red[0][tid] + red[1][tid] + red[2][tid] + red[3][tid];
        qf[tid * HD + h] = s + bq[h];
    }
}

// ---- 2: energies, mask-skipped. 2048 blocks x 256 thr; each wave = 4 rows. ----
__global__ __launch_bounds__(256) void energy_kernel(
    const float* __restrict__ sf, const float* __restrict__ qf,
    const float* __restrict__ Wc, const float* __restrict__ vv,
    const float* __restrict__ coverage, const int* __restrict__ mask,
    const int* __restrict__ is_cov_p, float* __restrict__ e_out)
{
    int b = blockIdx.x >> 7;                                  // 128 blocks per batch
    int wv = threadIdx.x >> 6, lane = threadIdx.x & 63;
    int rbase = (blockIdx.x & 127) * 16 + wv * 4;             // 4 rows per wave
    int l4 = lane * 4;
    int covflag = *is_cov_p;
    int row0 = b * LS + rbase;

    int4 mk = *reinterpret_cast<const int4*>(mask + row0);    // 4 masks, one 16B load
    bool mA = mk.x != 0, mB = mk.y != 0, mC = mk.z != 0, mD = mk.w != 0;

    float covA = 0.f, covB = 0.f, covC = 0.f, covD = 0.f;
    if (covflag) {
        if (mA) covA = coverage[row0 + 0];
        if (mB) covB = coverage[row0 + 1];
        if (mC) covC = coverage[row0 + 2];
        if (mD) covD = coverage[row0 + 3];
    }

    const float* qfr = qf + b * HD + l4;
    const float* pA = sf + (size_t)row0 * HD + l4;
    float accA = 0.f, accB = 0.f, accC = 0.f, accD = 0.f;

    #pragma unroll
    for (int it = 0; it < 4; ++it) {
        int o = it * 256;
        // shared operands: L1-hot reloads, keeps VGPR low
        f4 q  = ld4(qfr + o);
        f4 wc = ld4(Wc + o + l4);
        f4 vf = ld4(vv + o + l4);
        f4 sA, sB, sC, sD;
        if (mA) sA = ld4(pA + o);
        if (mB) sB = ld4(pA + HD + o);
        if (mC) sC = ld4(pA + 2 * HD + o);
        if (mD) sD = ld4(pA + 3 * HD + o);
        if (mA) accA += dotTanh(sA, q, wc, vf, covA);
        if (mB) accB += dotTanh(sB, q, wc, vf, covB);
        if (mC) accC += dotTanh(sC, q, wc, vf, covC);
        if (mD) accD += dotTanh(sD, q, wc, vf, covD);
    }

    // interleaved cross-lane reductions (4 independent chains pipeline)
    #pragma unroll
    for (int off = 32; off; off >>= 1) {
        accA += __shfl_xor(accA, off, 64);
        accB += __shfl_xor(accB, off, 64);
        accC += __shfl_xor(accC, off, 64);
        accD += __shfl_xor(accD, off, 64);
    }
    if (lane == 0) {
        f4 o;
        o.x = mA ? accA : -1e30f;
        o.y = mB ? accB : -1e30f;
        o.z = mC ? accC : -1e30f;
        o.w = mD ? accD : -1e30f;
        *reinterpret_cast<f4*>(e_out + row0) = o;
    }
}

// ---- 3: raw-exp weighted partial contexts (no max shift; |e| <= ~26 so safe).
//      Compacts nonzero rows, then branchless 4-deep load pipeline. ----
__global__ __launch_bounds__(256) void ctx_kernel(const float* __restrict__ e,
                                                  const float* __restrict__ states,
                                                  float* __restrict__ cpart) {
    int chunk = blockIdx.x;
    int b = blockIdx.y;
    int tid = threadIdx.x;            // 256
    __shared__ float wq[LPER];
    __shared__ int ridx[LPER];
    __shared__ int snnz;
    int base_row = b * LS + chunk * LPER;
    if (tid < 64) {                   // wave 0: compact nonzero rows
        float ev = (tid < LPER) ? e[base_row + tid] : -1e30f;
        float w = __expf(ev);         // masked rows -> exp(-1e30) = 0
        unsigned long long m = __ballot(w != 0.f);
        if (w != 0.f) {
            int pos = __popcll(m & ((1ull << tid) - 1));
            wq[pos] = w;
            ridx[pos] = tid;
        }
        if (tid == 0) snnz = __popcll(m);
    }
    __syncthreads();
    int nnz = snnz;
    int h0 = tid * 4;
    const float* sbase = states + (size_t)base_row * HD + h0;
    float ax = 0.f, ay = 0.f, az = 0.f, aw = 0.f;
    for (int i = 0; i < nnz; i += 4) {
        int j1 = i + 1, j2 = i + 2, j3 = i + 3;
        float w0 = wq[i];
        int   r0 = ridx[i];
        float w1 = (j1 < nnz) ? wq[j1] : 0.f;
        int   r1 = (j1 < nnz) ? ridx[j1] : r0;
        float w2 = (j2 < nnz) ? wq[j2] : 0.f;
        int   r2 = (j2 < nnz) ? ridx[j2] : r0;
        float w3 = (j3 < nnz) ? wq[j3] : 0.f;
        int   r3 = (j3 < nnz) ? ridx[j3] : r0;
        f4 s0 = ld4(sbase + ((size_t)r0 << 10));
        f4 s1 = ld4(sbase + ((size_t)r1 << 10));
        f4 s2 = ld4(sbase + ((size_t)r2 << 10));
        f4 s3 = ld4(sbase + ((size_t)r3 << 10));
        ax = fmaf(w0, s0.x, ax); ay = fmaf(w0, s0.y, ay); az = fmaf(w0, s0.z, az); aw = fmaf(w0, s0.w, aw);
        ax = fmaf(w1, s1.x, ax); ay = fmaf(w1, s1.y, ay); az = fmaf(w1, s1.z, az); aw = fmaf(w1, s1.w, aw);
        ax = fmaf(w2, s2.x, ax); ay = fmaf(w2, s2.y, ay); az = fmaf(w2, s2.z, az); aw = fmaf(w2, s2.w, aw);
        ax = fmaf(w3, s3.x, ax); ay = fmaf(w3, s3.y, ay); az = fmaf(w3, s3.z, az); aw = fmaf(w3, s3.w, aw);
    }
    f4 o; o.x = ax; o.y = ay; o.z = az; o.w = aw;
    *reinterpret_cast<f4*>(cpart + ((size_t)(b * LCHUNK + chunk)) * HD + h0) = o;  // unnormalized
}

// ---- 4 (merged): blocks 0..15 = per-batch softmax finalize; blocks 16..79 = cpart reduce ----
__global__ __launch_bounds__(1024) void mid_kernel(
    const float* __restrict__ e, const float* __restrict__ coverage,
    const float* __restrict__ cpart, float* __restrict__ scale,
    float* __restrict__ csum, float* __restrict__ out_align, float* __restrict__ out_newcov)
{
    __shared__ float redm[16], reds[16];
    __shared__ float red4[4][256];
    if (blockIdx.x < 16) {
        int b = blockIdx.x;
        int t = threadIdx.x;              // 1024
        int wv = t >> 6, lane = t & 63;
        float v0 = e[b * LS + t];
        float v1 = e[b * LS + t + 1024];
        float mx = fmaxf(v0, v1);
        #pragma unroll
        for (int off = 32; off; off >>= 1) mx = fmaxf(mx, __shfl_xor(mx, off, 64));
        if (lane == 0) redm[wv] = mx;
        __syncthreads();
        mx = redm[0];
        #pragma unroll
        for (int i = 1; i < 16; ++i) mx = fmaxf(mx, redm[i]);
        float e0 = __expf(v0 - mx), e1 = __expf(v1 - mx);
        float s = e0 + e1;
        #pragma unroll
        for (int off = 32; off; off >>= 1) s += __shfl_xor(s, off, 64);
        if (lane == 0) reds[wv] = s;
        __syncthreads();
        s = 0.f;
        #pragma unroll
        for (int i = 0; i < 16; ++i) s += reds[i];
        float invZ = 1.f / s;
        if (t == 0) scale[b] = __expf(-mx) * invZ;   // = 1 / sum(exp(e))
        int i0 = b * LS + t, i1 = i0 + 1024;
        float p0 = e0 * invZ, p1 = e1 * invZ;
        out_align[i0] = p0;
        out_align[i1] = p1;
        out_newcov[i0] = coverage[i0] + p0;
        out_newcov[i1] = coverage[i1] + p1;
    } else {
        int blk = blockIdx.x - 16;        // 0..63
        int tt = threadIdx.x & 255;
        int g = threadIdx.x >> 8;         // 0..3: each group sums 16 chunks
        int elem = blk * 256 + tt;        // 0..16383 = (b,h)
        int b = elem >> 10, h = elem & 1023;
        const float* p = cpart + (((size_t)(b * LCHUNK + g * 16)) << 10) + h;
        float s = 0.f;
        #pragma unroll
        for (int ch = 0; ch < 16; ++ch) s += p[(size_t)ch << 10];
        red4[g][tt] = s;
        __syncthreads();
        if (g == 0) csum[elem] = red4[0][tt] + red4[1][tt] + red4[2][tt] + red4[3][tt];
    }
}

// ---- 5: attn_h[b][h] = bout[h] + scale[b]*<Wout_c, csum[b]> + <Wout_q, query[b]> ----
__global__ void out_kernel(const float* __restrict__ csum, const float* __restrict__ query,
                           const float* __restrict__ Wout, const float* __restrict__ bout,
                           const float* __restrict__ scale, float* __restrict__ attn) {
    int h = blockIdx.x;
    int tid = threadIdx.x;            // 256
    int wv = tid >> 6, lane = tid & 63;
    int j0 = tid * 8;
    const float* wr = Wout + (size_t)h * (2 * HD);
    f4 w0 = ld4(wr + j0);
    f4 w1 = ld4(wr + j0 + 4);
    const float* src = (j0 < HD) ? (csum + j0) : (query + j0 - HD);   // waves 0,1: csum; 2,3: query
    __shared__ float red[4][NB];
    float acc[NB];
    #pragma unroll
    for (int b = 0; b < NB; ++b) {
        f4 x0 = ld4(src + b * HD);
        f4 x1 = ld4(src + b * HD + 4);
        acc[b] = w0.x * x0.x + w0.y * x0.y + w0.z * x0.z + w0.w * x0.w
               + w1.x * x1.x + w1.y * x1.y + w1.z * x1.z + w1.w * x1.w;
    }
    #pragma unroll
    for (int b = 0; b < NB; ++b) {
        float r = waveReduce(acc[b]);
        if (lane == 0) red[wv][b] = r;
    }
    __syncthreads();
    if (tid < NB) {
        float cpartial = red[0][tid] + red[1][tid];   // csum part
        float qpartial = red[2][tid] + red[3][tid];   // query part
        attn[tid * HD + h] = cpartial * scale[tid] + qpartial + bout[h];
    }
}

extern "C" void kernel_launch(void* const* d_in, const int* in_sizes, int n_in,
                              void* d_out, int out_size, void* d_ws, size_t ws_size,
                              hipStream_t stream) {
    const float* query    = (const float*)d_in[0];
    const float* states   = (const float*)d_in[1];
    const float* sf       = (const float*)d_in[2];
    const float* coverage = (const float*)d_in[3];
    const int*   mask     = (const int*)d_in[4];
    const int*   is_cov   = (const int*)d_in[5];
    const float* Wq       = (const float*)d_in[6];
    const float* bq       = (const float*)d_in[7];
    const float* Wc       = (const float*)d_in[8];
    const float* v        = (const float*)d_in[9];
    const float* Wout     = (const float*)d_in[10];
    const float* bout     = (const float*)d_in[11];

    float* out      = (float*)d_out;
    float* attn     = out;                 // (16,1,1024)  = 16384
    float* newcov   = out + 16384;         // (16,2048,1)  = 32768
    float* alignout = out + 49152;         // (16,2048,1)  = 32768

    float* w  = (float*)d_ws;
    float* qf      = w;                          // 16*1024    = 16384
    float* e       = w + 16384;                  // 16*2048    = 32768
    float* cpart   = w + 49152;                  // 16*64*1024 = 1048576
    float* scale   = w + 49152 + 1048576;        // 16
    float* csum    = scale + 16;                 // 16*1024

    // 1: query features (reads Wq once, 4 MB)
    qf_kernel<<<dim3(HD), dim3(256), 0, stream>>>(query, Wq, bq, qf);
    // 2: energies, mask-skipped (~64 MB of states_features on average)
    energy_kernel<<<dim3(2048), dim3(256), 0, stream>>>(sf, qf, Wc, v, coverage, mask, is_cov, e);
    // 3: raw-exp weighted partial contexts (~64 MB of states on average)
    ctx_kernel<<<dim3(LCHUNK, NB), dim3(256), 0, stream>>>(e, states, cpart);
    // 4: softmax finalize (align/newcov/scale) + cpart reduce, role-split
    mid_kernel<<<dim3(80), dim3(1024), 0, stream>>>(e, coverage, cpart, scale, csum, alignout, newcov);
    // 5: output projection (reads Wout once, 8 MB)
    out_kernel<<<dim3(HD), dim3(256), 0, stream>>>(csum, query, Wout, bout, scale, attn);
}

// Round 6
// 54.875 us; speedup vs baseline: 3.1684x; 1.0911x over previous
//
#include <hip/hip_runtime.h>
#include <cfloat>

#define HD 1024
#define LS 2048
#define NB 16
#define LCHUNK 64            // chunks per batch (32 rows each)
#define LPER   (LS / LCHUNK) // 32 rows per chunk

struct f4 { float x, y, z, w; };

__device__ inline f4 ld4(const float* p) { return *reinterpret_cast<const f4*>(p); }

__device__ inline float ftanh(float x) {
    x = fminf(10.f, fmaxf(-10.f, x));
    float t = __expf(2.f * x);
    return 1.f - 2.f * __builtin_amdgcn_rcpf(t + 1.f);
}

__device__ inline float dotTanh(const f4& s, const f4& q, const f4& wc, const f4& v, float covs) {
    return ftanh(s.x + q.x + covs * wc.x) * v.x
         + ftanh(s.y + q.y + covs * wc.y) * v.y
         + ftanh(s.z + q.z + covs * wc.z) * v.z
         + ftanh(s.w + q.w + covs * wc.w) * v.w;
}

__device__ inline float waveReduce(float v) {
    #pragma unroll
    for (int off = 32; off; off >>= 1) v += __shfl_xor(v, off, 64);
    return v;
}

// ---- 1: qf[b][h] = bq[h] + query[b,:] . Wq[h,:]  (block per h) ----
__global__ void qf_kernel(const float* __restrict__ query, const float* __restrict__ Wq,
                          const float* __restrict__ bq, float* __restrict__ qf) {
    int h = blockIdx.x;
    int tid = threadIdx.x;            // 256
    int wv = tid >> 6, lane = tid & 63;
    int k0 = tid * 4;
    f4 w = ld4(Wq + (size_t)h * HD + k0);
    __shared__ float red[4][NB];
    float acc[NB];
    #pragma unroll
    for (int b = 0; b < NB; ++b) {
        f4 q = ld4(query + b * HD + k0);
        acc[b] = w.x * q.x + w.y * q.y + w.z * q.z + w.w * q.w;
    }
    #pragma unroll
    for (int b = 0; b < NB; ++b) {
        float r = waveReduce(acc[b]);
        if (lane == 0) red[wv][b] = r;
    }
    __syncthreads();
    if (tid < NB) {
        float s = red[0][tid] + red[1][tid] + red[2][tid] + red[3][tid];
        qf[tid * HD + h] = s + bq[h];
    }
}

// ---- 2 (fused): per block = 32 rows of one batch.
//      Phase A: energies (8 rows per wave, interleaved reductions), mask-skipped.
//      Phase B: raw-exp weighted states partial (compaction + 4-deep pipeline). ----
__global__ __launch_bounds__(256) void fusedEC_kernel(
    const float* __restrict__ sf, const float* __restrict__ qf,
    const float* __restrict__ Wc, const float* __restrict__ vv,
    const float* __restrict__ coverage, const int* __restrict__ mask,
    const int* __restrict__ is_cov_p, const float* __restrict__ states,
    float* __restrict__ e_out, float* __restrict__ cpart)
{
    int chunk = blockIdx.x;                 // 0..63
    int b = blockIdx.y;                     // 0..15
    int tid = threadIdx.x;                  // 256
    int wv = tid >> 6, lane = tid & 63;
    int l4 = lane * 4;
    int base_row = b * LS + chunk * LPER;   // 32 rows
    int row0 = base_row + wv * 8;           // this wave's 8 rows

    __shared__ float e_loc[LPER];

    // --- phase A: energies ---
    int covflag = *is_cov_p;
    int4 mk0 = *reinterpret_cast<const int4*>(mask + row0);
    int4 mk1 = *reinterpret_cast<const int4*>(mask + row0 + 4);
    bool m[8] = { mk0.x != 0, mk0.y != 0, mk0.z != 0, mk0.w != 0,
                  mk1.x != 0, mk1.y != 0, mk1.z != 0, mk1.w != 0 };
    float cov[8];
    #pragma unroll
    for (int r = 0; r < 8; ++r) cov[r] = (covflag && m[r]) ? coverage[row0 + r] : 0.f;

    const float* qfr = qf + b * HD + l4;
    const float* ps = sf + (size_t)row0 * HD + l4;
    float acc[8] = {0.f, 0.f, 0.f, 0.f, 0.f, 0.f, 0.f, 0.f};

    #pragma unroll
    for (int it = 0; it < 4; ++it) {
        int o = it * 256;
        f4 q  = ld4(qfr + o);
        f4 wc = ld4(Wc + o + l4);
        f4 vf = ld4(vv + o + l4);
        f4 s[8];
        #pragma unroll
        for (int r = 0; r < 8; ++r) if (m[r]) s[r] = ld4(ps + (size_t)r * HD + o);
        #pragma unroll
        for (int r = 0; r < 8; ++r) if (m[r]) acc[r] += dotTanh(s[r], q, wc, vf, cov[r]);
    }

    // interleaved cross-lane reductions (8 independent chains pipeline)
    #pragma unroll
    for (int off = 32; off; off >>= 1) {
        #pragma unroll
        for (int r = 0; r < 8; ++r) acc[r] += __shfl_xor(acc[r], off, 64);
    }
    if (lane == 0) {
        float ev[8];
        #pragma unroll
        for (int r = 0; r < 8; ++r) ev[r] = m[r] ? acc[r] : -1e30f;
        f4 o0, o1;
        o0.x = ev[0]; o0.y = ev[1]; o0.z = ev[2]; o0.w = ev[3];
        o1.x = ev[4]; o1.y = ev[5]; o1.z = ev[6]; o1.w = ev[7];
        *reinterpret_cast<f4*>(e_out + row0) = o0;
        *reinterpret_cast<f4*>(e_out + row0 + 4) = o1;
        #pragma unroll
        for (int r = 0; r < 8; ++r) e_loc[wv * 8 + r] = ev[r];
    }
    __syncthreads();

    // --- phase B: compacted raw-exp weighted states accumulation ---
    __shared__ float wq[LPER];
    __shared__ int ridx[LPER];
    __shared__ int snnz;
    if (tid < 64) {                   // wave 0 compacts nonzero rows
        float ev = (tid < LPER) ? e_loc[tid] : -1e30f;
        float w = __expf(ev);         // masked -> exp(-1e30) = 0
        unsigned long long bm = __ballot(w != 0.f);
        if (w != 0.f) {
            int pos = __popcll(bm & ((1ull << tid) - 1));
            wq[pos] = w;
            ridx[pos] = tid;
        }
        if (tid == 0) snnz = __popcll(bm);
    }
    __syncthreads();
    int nnz = snnz;
    int h0 = tid * 4;
    const float* sbase = states + (size_t)base_row * HD + h0;
    float ax = 0.f, ay = 0.f, az = 0.f, aw = 0.f;
    for (int i = 0; i < nnz; i += 4) {
        int j1 = i + 1, j2 = i + 2, j3 = i + 3;
        float w0 = wq[i];
        int   r0 = ridx[i];
        float w1 = (j1 < nnz) ? wq[j1] : 0.f;
        int   r1 = (j1 < nnz) ? ridx[j1] : r0;
        float w2 = (j2 < nnz) ? wq[j2] : 0.f;
        int   r2 = (j2 < nnz) ? ridx[j2] : r0;
        float w3 = (j3 < nnz) ? wq[j3] : 0.f;
        int   r3 = (j3 < nnz) ? ridx[j3] : r0;
        f4 s0 = ld4(sbase + ((size_t)r0 << 10));
        f4 s1 = ld4(sbase + ((size_t)r1 << 10));
        f4 s2 = ld4(sbase + ((size_t)r2 << 10));
        f4 s3 = ld4(sbase + ((size_t)r3 << 10));
        ax = fmaf(w0, s0.x, ax); ay = fmaf(w0, s0.y, ay); az = fmaf(w0, s0.z, az); aw = fmaf(w0, s0.w, aw);
        ax = fmaf(w1, s1.x, ax); ay = fmaf(w1, s1.y, ay); az = fmaf(w1, s1.z, az); aw = fmaf(w1, s1.w, aw);
        ax = fmaf(w2, s2.x, ax); ay = fmaf(w2, s2.y, ay); az = fmaf(w2, s2.z, az); aw = fmaf(w2, s2.w, aw);
        ax = fmaf(w3, s3.x, ax); ay = fmaf(w3, s3.y, ay); az = fmaf(w3, s3.z, az); aw = fmaf(w3, s3.w, aw);
    }
    f4 o; o.x = ax; o.y = ay; o.z = az; o.w = aw;
    *reinterpret_cast<f4*>(cpart + ((size_t)(b * LCHUNK + chunk)) * HD + h0) = o;  // unnormalized
}

// ---- 3 (merged): blocks 0..15 = per-batch softmax finalize; blocks 16..79 = cpart reduce ----
__global__ __launch_bounds__(1024) void mid_kernel(
    const float* __restrict__ e, const float* __restrict__ coverage,
    const float* __restrict__ cpart, float* __restrict__ scale,
    float* __restrict__ csum, float* __restrict__ out_align, float* __restrict__ out_newcov)
{
    __shared__ float redm[16], reds[16];
    __shared__ float red4[4][256];
    if (blockIdx.x < 16) {
        int b = blockIdx.x;
        int t = threadIdx.x;              // 1024
        int wv = t >> 6, lane = t & 63;
        float v0 = e[b * LS + t];
        float v1 = e[b * LS + t + 1024];
        float mx = fmaxf(v0, v1);
        #pragma unroll
        for (int off = 32; off; off >>= 1) mx = fmaxf(mx, __shfl_xor(mx, off, 64));
        if (lane == 0) redm[wv] = mx;
        __syncthreads();
        mx = redm[0];
        #pragma unroll
        for (int i = 1; i < 16; ++i) mx = fmaxf(mx, redm[i]);
        float e0 = __expf(v0 - mx), e1 = __expf(v1 - mx);
        float s = e0 + e1;
        #pragma unroll
        for (int off = 32; off; off >>= 1) s += __shfl_xor(s, off, 64);
        if (lane == 0) reds[wv] = s;
        __syncthreads();
        s = 0.f;
        #pragma unroll
        for (int i = 0; i < 16; ++i) s += reds[i];
        float invZ = 1.f / s;
        if (t == 0) scale[b] = __expf(-mx) * invZ;   // = 1 / sum(exp(e))
        int i0 = b * LS + t, i1 = i0 + 1024;
        float p0 = e0 * invZ, p1 = e1 * invZ;
        out_align[i0] = p0;
        out_align[i1] = p1;
        out_newcov[i0] = coverage[i0] + p0;
        out_newcov[i1] = coverage[i1] + p1;
    } else {
        int blk = blockIdx.x - 16;        // 0..63
        int tt = threadIdx.x & 255;
        int g = threadIdx.x >> 8;         // 0..3: each group sums 16 chunks
        int elem = blk * 256 + tt;        // 0..16383 = (b,h)
        int b = elem >> 10, h = elem & 1023;
        const float* p = cpart + (((size_t)(b * LCHUNK + g * 16)) << 10) + h;
        float s = 0.f;
        #pragma unroll
        for (int ch = 0; ch < 16; ++ch) s += p[(size_t)ch << 10];
        red4[g][tt] = s;
        __syncthreads();
        if (g == 0) csum[elem] = red4[0][tt] + red4[1][tt] + red4[2][tt] + red4[3][tt];
    }
}

// ---- 4: attn_h[b][h] = bout[h] + scale[b]*<Wout_c, csum[b]> + <Wout_q, query[b]> ----
__global__ void out_kernel(const float* __restrict__ csum, const float* __restrict__ query,
                           const float* __restrict__ Wout, const float* __restrict__ bout,
                           const float* __restrict__ scale, float* __restrict__ attn) {
    int h = blockIdx.x;
    int tid = threadIdx.x;            // 256
    int wv = tid >> 6, lane = tid & 63;
    int j0 = tid * 8;
    const float* wr = Wout + (size_t)h * (2 * HD);
    f4 w0 = ld4(wr + j0);
    f4 w1 = ld4(wr + j0 + 4);
    const float* src = (j0 < HD) ? (csum + j0) : (query + j0 - HD);   // waves 0,1: csum; 2,3: query
    __shared__ float red[4][NB];
    float acc[NB];
    #pragma unroll
    for (int b = 0; b < NB; ++b) {
        f4 x0 = ld4(src + b * HD);
        f4 x1 = ld4(src + b * HD + 4);
        acc[b] = w0.x * x0.x + w0.y * x0.y + w0.z * x0.z + w0.w * x0.w
               + w1.x * x1.x + w1.y * x1.y + w1.z * x1.z + w1.w * x1.w;
    }
    #pragma unroll
    for (int b = 0; b < NB; ++b) {
        float r = waveReduce(acc[b]);
        if (lane == 0) red[wv][b] = r;
    }
    __syncthreads();
    if (tid < NB) {
        float cpartial = red[0][tid] + red[1][tid];   // csum part
        float qpartial = red[2][tid] + red[3][tid];   // query part
        attn[tid * HD + h] = cpartial * scale[tid] + qpartial + bout[h];
    }
}

extern "C" void kernel_launch(void* const* d_in, const int* in_sizes, int n_in,
                              void* d_out, int out_size, void* d_ws, size_t ws_size,
                              hipStream_t stream) {
    const float* query    = (const float*)d_in[0];
    const float* states   = (const float*)d_in[1];
    const float* sf       = (const float*)d_in[2];
    const float* coverage = (const float*)d_in[3];
    const int*   mask     = (const int*)d_in[4];
    const int*   is_cov   = (const int*)d_in[5];
    const float* Wq       = (const float*)d_in[6];
    const float* bq       = (const float*)d_in[7];
    const float* Wc       = (const float*)d_in[8];
    const float* v        = (const float*)d_in[9];
    const float* Wout     = (const float*)d_in[10];
    const float* bout     = (const float*)d_in[11];

    float* out      = (float*)d_out;
    float* attn     = out;                 // (16,1,1024)  = 16384
    float* newcov   = out + 16384;         // (16,2048,1)  = 32768
    float* alignout = out + 49152;         // (16,2048,1)  = 32768

    float* w  = (float*)d_ws;
    float* qf      = w;                          // 16*1024    = 16384
    float* e       = w + 16384;                  // 16*2048    = 32768
    float* cpart   = w + 49152;                  // 16*64*1024 = 1048576
    float* scale   = w + 49152 + 1048576;        // 16
    float* csum    = scale + 16;                 // 16*1024

    // 1: query features (reads Wq once, 4 MB)
    qf_kernel<<<dim3(HD), dim3(256), 0, stream>>>(query, Wq, bq, qf);
    // 2: fused energies + raw-exp weighted partial contexts (~128 MB masked streams)
    fusedEC_kernel<<<dim3(LCHUNK, NB), dim3(256), 0, stream>>>(
        sf, qf, Wc, v, coverage, mask, is_cov, states, e, cpart);
    // 3: softmax finalize (align/newcov/scale) + cpart reduce, role-split
    mid_kernel<<<dim3(80), dim3(1024), 0, stream>>>(e, coverage, cpart, scale, csum, alignout, newcov);
    // 4: output projection (reads Wout once, 8 MB)
    out_kernel<<<dim3(HD), dim3(256), 0, stream>>>(csum, query, Wout, bout, scale, attn);
}